// Round 2
// baseline (239.666 us; speedup 1.0000x reference)
//
#include <hip/hip_runtime.h>

// TTTConv: depthwise causal conv1d, B=4, N=4096, D=2048, K=4, fp32.
// out[b,n,d] = bias[d] + sum_{k=0..3} w[d,k] * x[b, n-3+k, d]  (x[t<0]=0)
// states[b,d,k] = x[b, N-4+k, d]  -- fused into the last n-chunk's blocks.
// Memory-bound: 128 MiB in + 128 MiB out -> ~42 us roofline at 6.3 TB/s.
// R1 -> R2: fused states kernel, T=8->16 (halo amplification 1.375->1.19x),
// non-temporal float4 stores for the write-once output stream.

constexpr int B = 4, N = 4096, D = 2048, K = 4;
constexpr int T = 16;             // timesteps per thread
constexpr int BLK = 256;          // threads per block
constexpr int DV = D / 4;         // 512 float4 lanes across channels
constexpr int DBLKS = DV / BLK;   // 2 d-blocks per row
constexpr int NCHUNKS = N / T;    // 256 n-chunks

typedef float v4f __attribute__((ext_vector_type(4)));

__global__ __launch_bounds__(BLK) void tttconv_fused(
    const float* __restrict__ x, const float* __restrict__ w,
    const float* __restrict__ bias, float* __restrict__ out,
    float* __restrict__ st)
{
    int bid = blockIdx.x;
    int b = bid / (NCHUNKS * DBLKS);
    int rem = bid % (NCHUNKS * DBLKS);
    int nchunk = rem / DBLKS;
    int dblk = rem % DBLKS;
    int dv = dblk * BLK + threadIdx.x;   // 0..511
    int d = dv * 4;
    int n0 = nchunk * T;

    // w is (D,K) row-major: w[d+c][0..3] -> 16 contiguous floats at d*K
    const float4* w4 = (const float4*)(w + (size_t)d * K);
    float4 wr0 = w4[0];
    float4 wr1 = w4[1];
    float4 wr2 = w4[2];
    float4 wr3 = w4[3];
    float4 bv = *(const float4*)(bias + d);

    const float* xbase = x + ((size_t)b * N) * D + d;
    float4 xin[T + K - 1];
    if (n0 >= K - 1) {
        // fast path: no left boundary in this chunk
        #pragma unroll
        for (int j = 0; j < T + K - 1; ++j)
            xin[j] = *(const float4*)(xbase + (size_t)(n0 - (K - 1) + j) * D);
    } else {
        #pragma unroll
        for (int j = 0; j < T + K - 1; ++j) {
            int n = n0 - (K - 1) + j;
            xin[j] = (n >= 0) ? *(const float4*)(xbase + (size_t)n * D)
                              : make_float4(0.f, 0.f, 0.f, 0.f);
        }
    }

    float* obase = out + ((size_t)b * N) * D + d;
    #pragma unroll
    for (int t = 0; t < T; ++t) {
        float4 acc = bv;
        // channel c uses wr_c; input row n0+t-3+k -> xin[t+k]
        acc.x += wr0.x * xin[t + 0].x + wr0.y * xin[t + 1].x + wr0.z * xin[t + 2].x + wr0.w * xin[t + 3].x;
        acc.y += wr1.x * xin[t + 0].y + wr1.y * xin[t + 1].y + wr1.z * xin[t + 2].y + wr1.w * xin[t + 3].y;
        acc.z += wr2.x * xin[t + 0].z + wr2.y * xin[t + 1].z + wr2.z * xin[t + 2].z + wr2.w * xin[t + 3].z;
        acc.w += wr3.x * xin[t + 0].w + wr3.y * xin[t + 1].w + wr3.z * xin[t + 2].w + wr3.w * xin[t + 3].w;
        v4f av = { acc.x, acc.y, acc.z, acc.w };
        __builtin_nontemporal_store(av, (v4f*)(obase + (size_t)(n0 + t) * D));
    }

    // conv_states: rows N-4..N-1 are xin[T-1..T+2] in the last chunk's blocks
    if (nchunk == NCHUNKS - 1) {
        float4* stp = (float4*)(st + ((size_t)b * D + d) * K);
        stp[0] = make_float4(xin[T - 1].x, xin[T].x, xin[T + 1].x, xin[T + 2].x);
        stp[1] = make_float4(xin[T - 1].y, xin[T].y, xin[T + 1].y, xin[T + 2].y);
        stp[2] = make_float4(xin[T - 1].z, xin[T].z, xin[T + 1].z, xin[T + 2].z);
        stp[3] = make_float4(xin[T - 1].w, xin[T].w, xin[T + 1].w, xin[T + 2].w);
    }
}

extern "C" void kernel_launch(void* const* d_in, const int* in_sizes, int n_in,
                              void* d_out, int out_size, void* d_ws, size_t ws_size,
                              hipStream_t stream)
{
    const float* x    = (const float*)d_in[0];
    const float* w    = (const float*)d_in[1];
    const float* bias = (const float*)d_in[2];
    float* out = (float*)d_out;
    float* st  = out + (size_t)B * N * D;

    tttconv_fused<<<B * NCHUNKS * DBLKS, BLK, 0, stream>>>(x, w, bias, out, st);
}